// Round 1
// baseline (384.179 us; speedup 1.0000x reference)
//
#include <hip/hip_runtime.h>
#include <math.h>

// LazyEqProp closed form:
//   The activity gate freezes every layer after its first effective update:
//   layer l's input becomes constant after step l-1, so inputs-prev == 0
//   exactly from step l+1 on. With steps=30 >= 3 layers the scan reduces to:
//     E  = x @ We^T + be
//     m0 = mean|E|  > eps ;  H0 = m0 * 0.5*tanh(E  @ W0^T + b0)
//     m1 = mean|H0| > eps ;  H1 = m1 * 0.5*tanh(H0 @ W1^T + b1)
//     m2 = mean|H1| > eps ;  H2 = m2 * 0.5*tanh(H1 @ W2^T + b2)
//     out = H2 @ Wh^T + bh
//   (h_upd = 0.5*h + 0.5*h_new with h==0 at the update step -> 0.5*tanh(z);
//    mask==0 rows stay exactly 0, which keeps downstream masks 0 too.)

#define TPB 256

constexpr int BM = 64, BN = 64, BK = 32;
constexpr float EPS_GATE = 0.01f;

// mask[row] = (mean_k |In[row,k]| > eps) ? 1 : 0
__global__ __launch_bounds__(TPB)
void rowmask_kernel(const float* __restrict__ In, float* __restrict__ mask, int K) {
    const int row = blockIdx.x;
    const float* p = In + (size_t)row * K;
    const int t = threadIdx.x;
    float s = 0.f;
    for (int k = t * 4; k < K; k += TPB * 4) {
        const float4 v = *(const float4*)(p + k);
        s += fabsf(v.x) + fabsf(v.y) + fabsf(v.z) + fabsf(v.w);
    }
#pragma unroll
    for (int off = 32; off > 0; off >>= 1) s += __shfl_down(s, off, 64);
    __shared__ float ws[TPB / 64];
    if ((t & 63) == 0) ws[t >> 6] = s;
    __syncthreads();
    if (t == 0) {
        float tot = 0.f;
#pragma unroll
        for (int i = 0; i < TPB / 64; ++i) tot += ws[i];
        mask[row] = (tot * (1.0f / (float)K) > EPS_GATE) ? 1.0f : 0.0f;
    }
}

// C[m,n] = act( sum_k A[m,k]*W[n,k] + bias[n] )
// ACT==0: identity.  ACT==1: mask[m] * 0.5*tanh(z)
// A: [M,K] row-major, W: [N,K] row-major (NT gemm), C: [M,N].
// M % BM == 0, N % BN == 0, K % BK == 0 (holds: 2048/1024/512/1024).
template <int ACT>
__global__ __launch_bounds__(TPB)
void gemm_nt_kernel(const float* __restrict__ A, const float* __restrict__ W,
                    const float* __restrict__ bias, const float* __restrict__ mask,
                    float* __restrict__ C, int N, int K) {
    __shared__ float As[BK][BM];  // transposed tiles: fragment reads are
    __shared__ float Ws[BK][BN];  // contiguous float4 -> conflict-free b128

    const int tid  = threadIdx.x;
    const int row0 = blockIdx.x * BM;
    const int col0 = blockIdx.y * BN;

    // staging: each thread loads 2 float4 of A and 2 of W per K-tile
    const int srow = tid >> 3;        // 0..31
    const int skc  = (tid & 7) << 2;  // 0,4,...,28
    const float* Ap0 = A + (size_t)(row0 + srow) * K + skc;
    const float* Ap1 = A + (size_t)(row0 + srow + 32) * K + skc;
    const float* Wp0 = W + (size_t)(col0 + srow) * K + skc;
    const float* Wp1 = W + (size_t)(col0 + srow + 32) * K + skc;

    const int ty = tid >> 4;  // 0..15 -> 4-row block
    const int tx = tid & 15;  // 0..15 -> 4-col block

    float acc[4][4] = {};

    for (int k0 = 0; k0 < K; k0 += BK) {
        const float4 a0 = *(const float4*)(Ap0 + k0);
        const float4 a1 = *(const float4*)(Ap1 + k0);
        const float4 w0 = *(const float4*)(Wp0 + k0);
        const float4 w1 = *(const float4*)(Wp1 + k0);
        __syncthreads();  // previous tile's compute done before overwrite
        As[skc + 0][srow] = a0.x; As[skc + 1][srow] = a0.y;
        As[skc + 2][srow] = a0.z; As[skc + 3][srow] = a0.w;
        As[skc + 0][srow + 32] = a1.x; As[skc + 1][srow + 32] = a1.y;
        As[skc + 2][srow + 32] = a1.z; As[skc + 3][srow + 32] = a1.w;
        Ws[skc + 0][srow] = w0.x; Ws[skc + 1][srow] = w0.y;
        Ws[skc + 2][srow] = w0.z; Ws[skc + 3][srow] = w0.w;
        Ws[skc + 0][srow + 32] = w1.x; Ws[skc + 1][srow + 32] = w1.y;
        Ws[skc + 2][srow + 32] = w1.z; Ws[skc + 3][srow + 32] = w1.w;
        __syncthreads();
#pragma unroll
        for (int kk = 0; kk < BK; ++kk) {
            const float4 av = *(const float4*)(&As[kk][ty << 2]);
            const float4 bv = *(const float4*)(&Ws[kk][tx << 2]);
            const float a[4] = {av.x, av.y, av.z, av.w};
            const float b[4] = {bv.x, bv.y, bv.z, bv.w};
#pragma unroll
            for (int i = 0; i < 4; ++i)
#pragma unroll
                for (int j = 0; j < 4; ++j)
                    acc[i][j] = fmaf(a[i], b[j], acc[i][j]);
        }
    }

#pragma unroll
    for (int i = 0; i < 4; ++i) {
        const int r = row0 + (ty << 2) + i;
        const float m = (ACT == 1) ? mask[r] : 1.0f;
        float* Crow = C + (size_t)r * N + col0 + (tx << 2);
#pragma unroll
        for (int j = 0; j < 4; ++j) {
            const int c = col0 + (tx << 2) + j;
            float z = acc[i][j] + bias[c];
            if (ACT == 1) z = m * (0.5f * tanhf(z));
            Crow[j] = z;
        }
    }
}

extern "C" void kernel_launch(void* const* d_in, const int* in_sizes, int n_in,
                              void* d_out, int out_size, void* d_ws, size_t ws_size,
                              hipStream_t stream) {
    const float* x  = (const float*)d_in[0];  // [2048,1024]
    const float* We = (const float*)d_in[1];  // [1024,1024]
    const float* be = (const float*)d_in[2];  // [1024]
    const float* W  = (const float*)d_in[3];  // [3,1024,1024]
    const float* b  = (const float*)d_in[4];  // [3,1024]
    const float* Wh = (const float*)d_in[5];  // [512,1024]
    const float* bh = (const float*)d_in[6];  // [512]
    // d_in[7] = steps (30); closed form valid for steps >= 3.

    const int B = 2048, H = 1024, O = 512;

    float* bufA = (float*)d_ws;                 // 8 MB
    float* bufB = bufA + (size_t)B * H;         // 8 MB
    float* msk  = bufB + (size_t)B * H;         // 8 KB
    float* out  = (float*)d_out;

    const dim3 blk(TPB);
    const dim3 gH(B / BM, H / BN);
    const dim3 gO(B / BM, O / BN);

    // E = x @ We^T + be
    gemm_nt_kernel<0><<<gH, blk, 0, stream>>>(x, We, be, nullptr, bufA, H, H);
    // layer 0
    rowmask_kernel<<<B, blk, 0, stream>>>(bufA, msk, H);
    gemm_nt_kernel<1><<<gH, blk, 0, stream>>>(bufA, W + (size_t)0 * H * H, b + 0 * H, msk, bufB, H, H);
    // layer 1
    rowmask_kernel<<<B, blk, 0, stream>>>(bufB, msk, H);
    gemm_nt_kernel<1><<<gH, blk, 0, stream>>>(bufB, W + (size_t)1 * H * H, b + 1 * H, msk, bufA, H, H);
    // layer 2
    rowmask_kernel<<<B, blk, 0, stream>>>(bufA, msk, H);
    gemm_nt_kernel<1><<<gH, blk, 0, stream>>>(bufA, W + (size_t)2 * H * H, b + 2 * H, msk, bufB, H, H);
    // head
    gemm_nt_kernel<0><<<gO, blk, 0, stream>>>(bufB, Wh, bh, nullptr, out, O, H);
}

// Round 2
// 94.785 us; speedup vs baseline: 4.0532x; 4.0532x over previous
//
#include <hip/hip_runtime.h>
#include <math.h>

// LazyEqProp closed form (verified round 1):
//   E  = x @ We^T + be
//   m0 = mean|E|  > eps ;  H0 = m0 * 0.5*tanh(E  @ W0^T + b0)
//   m1 = mean|H0| > eps ;  H1 = m1 * 0.5*tanh(H0 @ W1^T + b1)
//   m2 = mean|H1| > eps ;  H2 = m2 * 0.5*tanh(H1 @ W2^T + b2)
//   out = H2 @ Wh^T + bh
//
// This round: fp16 MFMA (16x16x32_f16) GEMMs. All GEMM operands live in a
// swizzled fp16 row format: row r, byte p holds element (p ^ ((r&7)<<4))/2.
// The XOR is baked into global storage, so LDS staging is a linear copy and
// fragment ds_read_b128 is bank-conflict-free (2-way max) with zero extra
// address math in the hot loop.

using half_t = _Float16;
typedef _Float16 f16x4 __attribute__((ext_vector_type(4)));
typedef _Float16 f16x8 __attribute__((ext_vector_type(8)));
typedef float    f32x4 __attribute__((ext_vector_type(4)));
typedef int      i32x4 __attribute__((ext_vector_type(4)));

constexpr int KDIM = 1024;          // contraction dim for every GEMM
constexpr int ROWB = KDIM * 2;      // bytes per swizzled fp16 row
constexpr float EPS_GATE = 0.01f;

__device__ __forceinline__ float tanh_fast(float z) {
    // tanh(z) = 1 - 2/(exp(2z)+1); abs err ~1e-7, safe at +-inf
    return 1.0f - 2.0f / (__expf(2.0f * z) + 1.0f);
}

// ---------------- convert fp32 -> swizzled fp16 (x, We, W, Wh in one grid) --
__global__ __launch_bounds__(256)
void convert_all(const float* __restrict__ x,  const float* __restrict__ We,
                 const float* __restrict__ W,  const float* __restrict__ Wh,
                 half_t* __restrict__ x16, half_t* __restrict__ We16,
                 half_t* __restrict__ W16, half_t* __restrict__ Wh16) {
    const int bid = blockIdx.x;
    const float* src; half_t* dst; int row;
    if (bid < 2048)      { src = x;  dst = x16;  row = bid; }
    else if (bid < 3072) { src = We; dst = We16; row = bid - 2048; }
    else if (bid < 6144) { src = W;  dst = W16;  row = bid - 3072; }
    else                 { src = Wh; dst = Wh16; row = bid - 6144; }
    const int t = threadIdx.x;  // 256 threads * 4 elems = 1024
    const f32x4 v = *(const f32x4*)(src + (size_t)row * KDIM + 4 * t);
    f16x4 h;
    h[0] = (half_t)v[0]; h[1] = (half_t)v[1]; h[2] = (half_t)v[2]; h[3] = (half_t)v[3];
    const int p = (8 * t) ^ ((row & 7) << 4);
    *(f16x4*)((char*)dst + (size_t)row * ROWB + p) = h;
}

// ---------------- row mask from swizzled fp16 rows (permutation-invariant) --
__global__ __launch_bounds__(64)
void rowmask16(const half_t* __restrict__ Hs, float* __restrict__ mask) {
    const int row = blockIdx.x;
    const int l = threadIdx.x;
    const f16x8* p = (const f16x8*)((const char*)Hs + (size_t)row * ROWB);
    float s = 0.f;
    const f16x8 a = p[l];
    const f16x8 b = p[l + 64];
#pragma unroll
    for (int j = 0; j < 8; ++j) s += fabsf((float)a[j]) + fabsf((float)b[j]);
#pragma unroll
    for (int off = 32; off > 0; off >>= 1) s += __shfl_down(s, off, 64);
    if (l == 0) mask[row] = (s * (1.0f / (float)KDIM) > EPS_GATE) ? 1.0f : 0.0f;
}

// ---------------- fp16 MFMA GEMM: O[m,n] = epi( sum_k P[m,k]*Q[n,k] + bias[n] )
// P: [M][K] swz-f16 (activations), Q: [N][K] swz-f16 (weights).
// Tile 128(m) x 64(n) x 64(k); 4 waves, each 64(m) x 32(n).
// MFMA operands swapped (A<-Q rows, B<-P rows) so a lane's 4 accs are 4
// consecutive n -> 8B stores.
// EPI: 0 = identity->swz f16, 1 = mask*0.5*tanh->swz f16, 2 = identity->f32
template <int EPI>
__global__ __launch_bounds__(256)
void gemm16(const half_t* __restrict__ P, const half_t* __restrict__ Q,
            const float* __restrict__ bias, const float* __restrict__ mask,
            void* __restrict__ Out, int Nout) {
    __shared__ alignas(16) half_t Pt[128 * 64];  // 16 KB, swizzled rows (128B each)
    __shared__ alignas(16) half_t Qt[64 * 64];   //  8 KB

    const int tid = threadIdx.x;
    const int m0 = blockIdx.x * 128;
    const int n0 = blockIdx.y * 64;

    // --- staging map: 1536 16B granules; granule G: G<1024 -> P row G>>3, else Q
    const char* gs[6]; char* ls[6];
#pragma unroll
    for (int i = 0; i < 6; ++i) {
        const int G = tid + 256 * i;
        if (i < 4) {  // G < 1024 always
            gs[i] = (const char*)P + (size_t)(m0 + (G >> 3)) * ROWB + (G & 7) * 16;
            ls[i] = (char*)Pt + G * 16;
        } else {
            const int G2 = G - 1024;
            gs[i] = (const char*)Q + (size_t)(n0 + (G2 >> 3)) * ROWB + (G2 & 7) * 16;
            ls[i] = (char*)Qt + G2 * 16;
        }
    }

    // --- per-lane fragment read offsets (XOR swizzle; row&7 == lane&7)
    const int lane = tid & 63;
    const int w = tid >> 6;
    const int wm = (w & 1) * 64;    // wave m-offset
    const int wn = (w >> 1) * 32;   // wave n-offset
    const int l15 = lane & 15, l4 = lane >> 4;
    const int pxor = (lane & 7) << 4;
    const int off0 = (l4 * 16) ^ pxor;   // k-half 0
    const int off1 = off0 ^ 64;          // k-half 1

    i32x4 r[6];
#pragma unroll
    for (int i = 0; i < 6; ++i) r[i] = *(const i32x4*)gs[i];

    f32x4 acc[2][4] = {};  // [i = n-frag][j = m-frag]

    for (int s = 0; s < KDIM / 64; ++s) {
        __syncthreads();  // prior frag reads done; vmcnt drained -> r valid
#pragma unroll
        for (int i = 0; i < 6; ++i) *(i32x4*)ls[i] = r[i];
        __syncthreads();  // ds_writes visible
        if (s + 1 < KDIM / 64) {
            const int go = (s + 1) * 128;
#pragma unroll
            for (int i = 0; i < 6; ++i) r[i] = *(const i32x4*)(gs[i] + go);
        }
#pragma unroll
        for (int h = 0; h < 2; ++h) {
            const int ko = (h == 0) ? off0 : off1;
            f16x8 qa[2], pb[4];
#pragma unroll
            for (int i = 0; i < 2; ++i)
                qa[i] = *(const f16x8*)((char*)Qt + (wn + i * 16 + l15) * 128 + ko);
#pragma unroll
            for (int j = 0; j < 4; ++j)
                pb[j] = *(const f16x8*)((char*)Pt + (wm + j * 16 + l15) * 128 + ko);
#pragma unroll
            for (int i = 0; i < 2; ++i)
#pragma unroll
                for (int j = 0; j < 4; ++j)
                    acc[i][j] = __builtin_amdgcn_mfma_f32_16x16x32_f16(qa[i], pb[j], acc[i][j], 0, 0, 0);
        }
    }

    // --- epilogue: lane holds m = m0+wm+j*16+(lane&15), n = n0+wn+i*16+(lane>>4)*4+e
#pragma unroll
    for (int j = 0; j < 4; ++j) {
        const int m = m0 + wm + j * 16 + l15;
        const float msk = (EPI == 1) ? mask[m] : 1.0f;
#pragma unroll
        for (int i = 0; i < 2; ++i) {
            const int n = n0 + wn + i * 16 + l4 * 4;
            const f32x4 bz = *(const f32x4*)(bias + n);
            float v[4];
#pragma unroll
            for (int e = 0; e < 4; ++e) {
                v[e] = acc[i][j][e] + bz[e];
                if (EPI == 1) v[e] = msk * (0.5f * tanh_fast(v[e]));
            }
            if (EPI == 2) {
                f32x4 o; o[0] = v[0]; o[1] = v[1]; o[2] = v[2]; o[3] = v[3];
                *(f32x4*)((float*)Out + (size_t)m * Nout + n) = o;
            } else {
                f16x4 hv;
                hv[0] = (half_t)v[0]; hv[1] = (half_t)v[1];
                hv[2] = (half_t)v[2]; hv[3] = (half_t)v[3];
                const int p = (n * 2) ^ ((m & 7) << 4);
                *(f16x4*)((char*)Out + (size_t)m * ROWB + p) = hv;
            }
        }
    }
}

extern "C" void kernel_launch(void* const* d_in, const int* in_sizes, int n_in,
                              void* d_out, int out_size, void* d_ws, size_t ws_size,
                              hipStream_t stream) {
    const float* x  = (const float*)d_in[0];  // [2048,1024]
    const float* We = (const float*)d_in[1];  // [1024,1024]
    const float* be = (const float*)d_in[2];  // [1024]
    const float* W  = (const float*)d_in[3];  // [3,1024,1024]
    const float* b  = (const float*)d_in[4];  // [3,1024]
    const float* Wh = (const float*)d_in[5];  // [512,1024]
    const float* bh = (const float*)d_in[6];  // [512]

    const int B = 2048, H = 1024, O = 512;

    // ws layout (fp16 elems): s0 is reused as x16 then H0 then H2.
    half_t* s0   = (half_t*)d_ws;                     // 2048*1024 (4 MB)  x16/H0/H2
    half_t* s1   = s0 + (size_t)B * H;                // 2048*1024 (4 MB)  E/H1
    half_t* We16 = s1 + (size_t)B * H;                // 1M (2 MB)
    half_t* W16  = We16 + (size_t)H * H;              // 3M (6 MB)
    half_t* Wh16 = W16 + (size_t)3 * H * H;           // 0.5M (1 MB)
    float*  msk  = (float*)(Wh16 + (size_t)O * H);    // 2048 floats
    float*  out  = (float*)d_out;

    const dim3 blk(256);

    convert_all<<<6656, blk, 0, stream>>>(x, We, W, Wh, s0, We16, W16, Wh16);

    const dim3 gH(B / 128, H / 64);  // 16 x 16
    const dim3 gO(B / 128, O / 64);  // 16 x 8

    // E = x @ We^T + be
    gemm16<0><<<gH, blk, 0, stream>>>(s0, We16, be, nullptr, s1, H);
    // layer 0
    rowmask16<<<B, dim3(64), 0, stream>>>(s1, msk);
    gemm16<1><<<gH, blk, 0, stream>>>(s1, W16 + (size_t)0 * H * H, b + 0 * H, msk, s0, H);
    // layer 1
    rowmask16<<<B, dim3(64), 0, stream>>>(s0, msk);
    gemm16<1><<<gH, blk, 0, stream>>>(s0, W16 + (size_t)1 * H * H, b + 1 * H, msk, s1, H);
    // layer 2
    rowmask16<<<B, dim3(64), 0, stream>>>(s1, msk);
    gemm16<1><<<gH, blk, 0, stream>>>(s1, W16 + (size_t)2 * H * H, b + 2 * H, msk, s0, H);
    // head
    gemm16<2><<<gO, blk, 0, stream>>>(s0, Wh16, bh, nullptr, out, O);
}

// Round 3
// 87.325 us; speedup vs baseline: 4.3994x; 1.0854x over previous
//
#include <hip/hip_runtime.h>
#include <math.h>

// LazyEqProp closed form (verified rounds 1-2):
//   E  = x @ We^T + be
//   m0 = mean|E|  > eps ;  H0 = m0 * 0.5*tanh(E  @ W0^T + b0)
//   m1 = mean|H0| > eps ;  H1 = m1 * 0.5*tanh(H0 @ W1^T + b1)
//   m2 = mean|H1| > eps ;  H2 = m2 * 0.5*tanh(H1 @ W2^T + b2)
//   out = H2 @ Wh^T + bh
//
// Round 3: 6 dispatches (convert + 5 fused gemms).
//  - row-mask fused into GEMM staging (packed-f16 |.| accumulation)
//  - LDS double-buffer, ONE barrier per K-step, loads issued post-barrier
//  - XCD-aware block map: per-XCD A-panel (512KB) + Q (2MB) stay L2-resident

using half_t = _Float16;
typedef _Float16 f16x2 __attribute__((ext_vector_type(2)));
typedef _Float16 f16x4 __attribute__((ext_vector_type(4)));
typedef _Float16 f16x8 __attribute__((ext_vector_type(8)));
typedef float    f32x4 __attribute__((ext_vector_type(4)));
typedef int      i32x4 __attribute__((ext_vector_type(4)));

constexpr int KDIM = 1024;
constexpr int ROWB = KDIM * 2;  // bytes per swizzled f16 row
constexpr float EPS_GATE = 0.01f;

__device__ __forceinline__ float tanh_fast(float z) {
    // tanh(z) = 1 - 2/(exp(2z)+1); abs err ~1e-7, safe at +-inf
    return 1.0f - 2.0f / (__expf(2.0f * z) + 1.0f);
}

// ---- fp32 -> swizzled fp16 (row r, byte p holds element (p ^ ((r&7)<<4))/2)
__global__ __launch_bounds__(256)
void convert_all(const float* __restrict__ x,  const float* __restrict__ We,
                 const float* __restrict__ W,  const float* __restrict__ Wh,
                 half_t* __restrict__ x16, half_t* __restrict__ We16,
                 half_t* __restrict__ W16, half_t* __restrict__ Wh16) {
    const int bid = blockIdx.x;
    const float* src; half_t* dst; int row;
    if (bid < 2048)      { src = x;  dst = x16;  row = bid; }
    else if (bid < 3072) { src = We; dst = We16; row = bid - 2048; }
    else if (bid < 6144) { src = W;  dst = W16;  row = bid - 3072; }
    else                 { src = Wh; dst = Wh16; row = bid - 6144; }
    const int t = threadIdx.x;
    const f32x4 v = *(const f32x4*)(src + (size_t)row * KDIM + 4 * t);
    f16x4 h;
    h[0] = (half_t)v[0]; h[1] = (half_t)v[1]; h[2] = (half_t)v[2]; h[3] = (half_t)v[3];
    const int p = (8 * t) ^ ((row & 7) << 4);
    *(f16x4*)((char*)dst + (size_t)row * ROWB + p) = h;
}

// ---- fused NT gemm: O[m,n] = epi( sum_k P[m,k]*Q[n,k] + bias[n] )
// P: [M][1024] swz-f16, Q: [N][1024] swz-f16. Tile 128m x 64n x 64k, 4 waves.
// EPI: 0 = bias -> swz f16;  1 = rowmask(P)*0.5*tanh(.+bias) -> swz f16;
//      2 = bias -> f32.
// Rowmask fused: each thread's 4 staged P granules belong to rows
// (tid>>3)+32i; |values| accumulate in packed f16; 8 threads/row shfl-reduce.
template <int EPI>
__global__ __launch_bounds__(256)
void gemm_fused(const half_t* __restrict__ P, const half_t* __restrict__ Q,
                const float* __restrict__ bias, void* __restrict__ Out, int Nout) {
    // [0,16K) Pt0 | [16K,32K) Pt1 | [32K,40K) Qt0 | [40K,48K) Qt1
    __shared__ alignas(16) char smem[49152];

    const int tid = threadIdx.x;
    const int bid = blockIdx.x;
    // XCD-aware map: xcd = bid&7 owns m-tiles {2x,2x+1} across all n-tiles.
    const int m0 = ((bid & 7) * 2 + ((bid >> 3) & 1)) * 128;
    const int n0 = (bid >> 4) * 64;

    // staging: P 1024 granules/step (4/thread), Q 512 (2/thread); linear copy
    const char* gP[4]; int lP[4];
#pragma unroll
    for (int i = 0; i < 4; ++i) {
        const int G = tid + 256 * i;
        gP[i] = (const char*)P + (size_t)(m0 + (G >> 3)) * ROWB + (G & 7) * 16;
        lP[i] = G * 16;
    }
    const char* gQ[2]; int lQ[2];
#pragma unroll
    for (int c = 0; c < 2; ++c) {
        const int g = 2 * tid + c;
        gQ[c] = (const char*)Q + (size_t)(n0 + (g >> 3)) * ROWB + (g & 7) * 16;
        lQ[c] = g * 16;
    }

    const int lane = tid & 63;
    const int w = tid >> 6;
    const int wm = (w & 1) * 64;    // wave m-offset
    const int wn = (w >> 1) * 32;   // wave n-offset
    const int l15 = lane & 15, l4 = lane >> 4;
    const int off0 = (l4 * 16) ^ ((lane & 7) << 4);
    const int off1 = off0 ^ 64;

    i32x4 rp[4], rq[2];
#pragma unroll
    for (int i = 0; i < 4; ++i) rp[i] = *(const i32x4*)gP[i];
#pragma unroll
    for (int c = 0; c < 2; ++c) rq[c] = *(const i32x4*)gQ[c];

    f16x2 macc[4] = {};        // packed |P| row-sums (EPI==1 only)
    f32x4 acc[2][4] = {};      // [n-frag][m-frag]

    for (int s = 0; s < 16; ++s) {
        const int bpo = (s & 1) * 16384;
        const int bqo = 32768 + (s & 1) * 8192;
        // write tile s (regs loaded last iteration; vmcnt satisfied by then)
#pragma unroll
        for (int i = 0; i < 4; ++i) *(i32x4*)(smem + bpo + lP[i]) = rp[i];
#pragma unroll
        for (int c = 0; c < 2; ++c) *(i32x4*)(smem + bqo + lQ[c]) = rq[c];
        if (EPI == 1) {
#pragma unroll
            for (int i = 0; i < 4; ++i)
#pragma unroll
                for (int k = 0; k < 4; ++k)
                    macc[i] += __builtin_bit_cast(f16x2, rp[i][k] & 0x7fff7fff);
        }
        __syncthreads();
        // issue next tile's loads early (land during MFMA phase; T14)
        if (s < 15) {
            const int go = (s + 1) * 128;
#pragma unroll
            for (int i = 0; i < 4; ++i) rp[i] = *(const i32x4*)(gP[i] + go);
#pragma unroll
            for (int c = 0; c < 2; ++c) rq[c] = *(const i32x4*)(gQ[c] + go);
        }
        const char* PtB = smem + bpo;
        const char* QtB = smem + bqo;
#pragma unroll
        for (int h = 0; h < 2; ++h) {
            const int ko = h ? off1 : off0;
            f16x8 qa[2], pb[4];
#pragma unroll
            for (int i = 0; i < 2; ++i)
                qa[i] = *(const f16x8*)(QtB + (wn + i * 16 + l15) * 128 + ko);
#pragma unroll
            for (int j = 0; j < 4; ++j)
                pb[j] = *(const f16x8*)(PtB + (wm + j * 16 + l15) * 128 + ko);
#pragma unroll
            for (int i = 0; i < 2; ++i)
#pragma unroll
                for (int j = 0; j < 4; ++j)
                    acc[i][j] = __builtin_amdgcn_mfma_f32_16x16x32_f16(qa[i], pb[j], acc[i][j], 0, 0, 0);
        }
    }

    // ---- finalize row masks: 8 consecutive lanes share a row
    float* msum = (float*)smem;  // overlays Pt0; last reads were buf1 (safe)
    if (EPI == 1) {
#pragma unroll
        for (int i = 0; i < 4; ++i) {
            float s = (float)macc[i][0] + (float)macc[i][1];
            s += __shfl_xor(s, 1, 64);
            s += __shfl_xor(s, 2, 64);
            s += __shfl_xor(s, 4, 64);
            if ((tid & 7) == 0) msum[(tid >> 3) + 32 * i] = s;
        }
        __syncthreads();
    }

    // ---- epilogue: lane holds m = m0+wm+j*16+l15, n = n0+wn+i*16+l4*4+e
#pragma unroll
    for (int j = 0; j < 4; ++j) {
        const int ml = wm + j * 16 + l15;
        const int m = m0 + ml;
        float msk = 1.0f;
        if (EPI == 1) msk = (msum[ml] * (1.0f / 1024.0f) > EPS_GATE) ? 1.0f : 0.0f;
#pragma unroll
        for (int i = 0; i < 2; ++i) {
            const int n = n0 + wn + i * 16 + l4 * 4;
            const f32x4 bz = *(const f32x4*)(bias + n);
            float v[4];
#pragma unroll
            for (int e = 0; e < 4; ++e) {
                v[e] = acc[i][j][e] + bz[e];
                if (EPI == 1) v[e] = msk * (0.5f * tanh_fast(v[e]));
            }
            if (EPI == 2) {
                f32x4 o; o[0] = v[0]; o[1] = v[1]; o[2] = v[2]; o[3] = v[3];
                *(f32x4*)((float*)Out + (size_t)m * Nout + n) = o;
            } else {
                f16x4 hv;
                hv[0] = (half_t)v[0]; hv[1] = (half_t)v[1];
                hv[2] = (half_t)v[2]; hv[3] = (half_t)v[3];
                const int p = (n * 2) ^ ((m & 7) << 4);
                *(f16x4*)((char*)Out + (size_t)m * ROWB + p) = hv;
            }
        }
    }
}

extern "C" void kernel_launch(void* const* d_in, const int* in_sizes, int n_in,
                              void* d_out, int out_size, void* d_ws, size_t ws_size,
                              hipStream_t stream) {
    const float* x  = (const float*)d_in[0];  // [2048,1024]
    const float* We = (const float*)d_in[1];  // [1024,1024]
    const float* be = (const float*)d_in[2];  // [1024]
    const float* W  = (const float*)d_in[3];  // [3,1024,1024]
    const float* b  = (const float*)d_in[4];  // [3,1024]
    const float* Wh = (const float*)d_in[5];  // [512,1024]
    const float* bh = (const float*)d_in[6];  // [512]

    const int B = 2048, H = 1024, O = 512;

    half_t* s0   = (half_t*)d_ws;                   // x16 / H0 / H2
    half_t* s1   = s0 + (size_t)B * H;              // E / H1
    half_t* We16 = s1 + (size_t)B * H;
    half_t* W16  = We16 + (size_t)H * H;
    half_t* Wh16 = W16 + (size_t)3 * H * H;
    float*  out  = (float*)d_out;

    convert_all<<<6656, 256, 0, stream>>>(x, We, W, Wh, s0, We16, W16, Wh16);

    // E = x @ We^T + be
    gemm_fused<0><<<256, 256, 0, stream>>>(s0, We16, be, s1, H);
    // H0, H1, H2 (mask fused)
    gemm_fused<1><<<256, 256, 0, stream>>>(s1, W16,                     b,         s0, H);
    gemm_fused<1><<<256, 256, 0, stream>>>(s0, W16 + (size_t)H * H,     b + H,     s1, H);
    gemm_fused<1><<<256, 256, 0, stream>>>(s1, W16 + (size_t)2 * H * H, b + 2 * H, s0, H);
    // head
    gemm_fused<2><<<128, 256, 0, stream>>>(s0, Wh16, bh, out, O);
}

// Round 4
// 71.526 us; speedup vs baseline: 5.3712x; 1.2209x over previous
//
#include <hip/hip_runtime.h>
#include <math.h>

// LazyEqProp closed form (verified rounds 1-3):
//   E  = x @ We^T + be
//   m0 = mean|E|  > eps ;  H0 = m0 * 0.5*tanh(E  @ W0^T + b0)
//   m1 = mean|H0| > eps ;  H1 = m1 * 0.5*tanh(H0 @ W1^T + b1)
//   m2 = mean|H1| > eps ;  H2 = m2 * 0.5*tanh(H1 @ W2^T + b2)
//   out = H2 @ Wh^T + bh
//
// Round 4: 6 dispatches. GEMM rebuilt:
//  - 512 threads / 8 waves per block (2 waves/SIMD -> MFMA hides staging)
//  - global_load_lds width=16 staging (pre-swizzled global => linear LDS dest)
//  - 2-phase loop: sync -> STAGE(next) -> ds_read+MFMA(cur); 1 barrier/step
//  - row masks produced in the *producer* gemm epilogue via atomicAdd partials

using half_t = _Float16;
typedef _Float16 f16x4 __attribute__((ext_vector_type(4)));
typedef _Float16 f16x8 __attribute__((ext_vector_type(8)));
typedef float    f32x4 __attribute__((ext_vector_type(4)));

constexpr int KDIM = 1024;
constexpr int ROWB = KDIM * 2;  // bytes per swizzled f16 row
constexpr float EPS_GATE = 0.01f;

__device__ __forceinline__ float tanh_fast(float z) {
    return 1.0f - 2.0f / (__expf(2.0f * z) + 1.0f);  // safe at +-inf
}

__device__ __forceinline__ void gload16(const void* g, void* l) {
    __builtin_amdgcn_global_load_lds(
        (const __attribute__((address_space(1))) void*)g,
        (__attribute__((address_space(3))) void*)l, 16, 0, 0);
}

// ---- fp32 -> swizzled fp16 (row r, byte p holds element (p ^ ((r&7)<<4))/2)
//      + zero the 3 row-sum accumulators (blocks 0..5)
__global__ __launch_bounds__(256)
void convert_all(const float* __restrict__ x,  const float* __restrict__ We,
                 const float* __restrict__ W,  const float* __restrict__ Wh,
                 half_t* __restrict__ x16, half_t* __restrict__ We16,
                 half_t* __restrict__ W16, half_t* __restrict__ Wh16,
                 float* __restrict__ msum) {
    const int bid = blockIdx.x;
    const int t = threadIdx.x;
    if (bid < 6) ((f32x4*)msum)[bid * 256 + t] = f32x4{0.f, 0.f, 0.f, 0.f};
    const float* src; half_t* dst; int row;
    if (bid < 2048)      { src = x;  dst = x16;  row = bid; }
    else if (bid < 3072) { src = We; dst = We16; row = bid - 2048; }
    else if (bid < 6144) { src = W;  dst = W16;  row = bid - 3072; }
    else                 { src = Wh; dst = Wh16; row = bid - 6144; }
    const f32x4 v = *(const f32x4*)(src + (size_t)row * KDIM + 4 * t);
    f16x4 h;
    h[0] = (half_t)v[0]; h[1] = (half_t)v[1]; h[2] = (half_t)v[2]; h[3] = (half_t)v[3];
    const int p = (8 * t) ^ ((row & 7) << 4);
    *(f16x4*)((char*)dst + (size_t)row * ROWB + p) = h;
}

// ---- NT gemm: O[m,n] = epi( sum_k P[m,k]*Q[n,k] + bias[n] )
// P,Q swizzled f16. Tile 128m x 64n x 64k; 8 waves (4m x 2n), wave tile 32x32.
// EPI: 0 = bias -> swz f16; 1 = mask(msum_in)*0.5*tanh(.+bias) -> swz f16;
//      2 = bias -> f32.  EMIT: atomicAdd per-row |out| partials into msum_out.
template <int EPI, bool EMIT>
__global__ __launch_bounds__(512)
void gemm8w(const half_t* __restrict__ P, const half_t* __restrict__ Q,
            const float* __restrict__ bias, const float* __restrict__ msum_in,
            float* __restrict__ msum_out, void* __restrict__ Out, int Nout) {
    // [0,16K) Pt buf0 | [16K,32K) Pt buf1 | [32K,40K) Qt buf0 | [40K,48K) Qt buf1
    __shared__ alignas(16) char smem[49152];

    const int tid = threadIdx.x;
    const int bid = blockIdx.x;
    // XCD-aware: xcd = bid&7 owns m-tiles {2x,2x+1} across all n-tiles.
    const int m0 = ((bid & 7) * 2 + ((bid >> 3) & 1)) * 128;
    const int n0 = (bid >> 4) * 64;

    // staging: 3 x 16B granules/thread, LDS dest = uniform base + lane*16
    const char* gP0 = (const char*)P + (size_t)(m0 + (tid >> 3)) * ROWB + (tid & 7) * 16;
    const char* gP1 = gP0 + (size_t)64 * ROWB;
    const char* gQ  = (const char*)Q + (size_t)(n0 + (tid >> 3)) * ROWB + (tid & 7) * 16;
    const int ldsT = tid * 16;

    const int lane = tid & 63;
    const int w = tid >> 6;
    const int wm = (w & 3) * 32;
    const int wn = (w >> 2) * 32;
    const int l15 = lane & 15, l4 = lane >> 4;
    const int off0 = (l4 * 16) ^ ((lane & 7) << 4);
    const int off1 = off0 ^ 64;

    f32x4 acc[2][2] = {};  // [n-frag][m-frag]

    // prologue: stage tile 0 into buf 0
    gload16(gP0, smem + ldsT);
    gload16(gP1, smem + 8192 + ldsT);
    gload16(gQ, smem + 32768 + ldsT);

    for (int s = 0; s < 16; ++s) {
        const int b = s & 1;
        __syncthreads();  // drains vmcnt(0): buf b ready; buf b^1 reads done
        if (s < 15) {     // stage tile s+1 into buf b^1 (lands during MFMA)
            const int go = (s + 1) * 128;
            const int bp = (b ^ 1) * 16384, bq = 32768 + (b ^ 1) * 8192;
            gload16(gP0 + go, smem + bp + ldsT);
            gload16(gP1 + go, smem + bp + 8192 + ldsT);
            gload16(gQ + go, smem + bq + ldsT);
        }
        const char* PtB = smem + b * 16384;
        const char* QtB = smem + 32768 + b * 8192;
#pragma unroll
        for (int h = 0; h < 2; ++h) {
            const int ko = h ? off1 : off0;
            f16x8 qa[2], pb[2];
#pragma unroll
            for (int i = 0; i < 2; ++i)
                qa[i] = *(const f16x8*)(QtB + (wn + i * 16 + l15) * 128 + ko);
#pragma unroll
            for (int j = 0; j < 2; ++j)
                pb[j] = *(const f16x8*)(PtB + (wm + j * 16 + l15) * 128 + ko);
#pragma unroll
            for (int i = 0; i < 2; ++i)
#pragma unroll
                for (int j = 0; j < 2; ++j)
                    acc[i][j] = __builtin_amdgcn_mfma_f32_16x16x32_f16(qa[i], pb[j], acc[i][j], 0, 0, 0);
        }
    }

    // ---- epilogue: lane holds m = m0+wm+j*16+l15, n = n0+wn+i*16+l4*4+e
#pragma unroll
    for (int j = 0; j < 2; ++j) {
        const int m = m0 + wm + j * 16 + l15;
        float msk = 1.0f;
        if (EPI == 1) msk = (msum_in[m] * (1.0f / 1024.0f) > EPS_GATE) ? 1.0f : 0.0f;
        float rsum = 0.0f;
#pragma unroll
        for (int i = 0; i < 2; ++i) {
            const int n = n0 + wn + i * 16 + l4 * 4;
            const f32x4 bz = *(const f32x4*)(bias + n);
            float v[4];
#pragma unroll
            for (int e = 0; e < 4; ++e) {
                v[e] = acc[i][j][e] + bz[e];
                if (EPI == 1) v[e] = msk * (0.5f * tanh_fast(v[e]));
                if (EMIT) rsum += fabsf(v[e]);
            }
            if (EPI == 2) {
                f32x4 o; o[0] = v[0]; o[1] = v[1]; o[2] = v[2]; o[3] = v[3];
                *(f32x4*)((float*)Out + (size_t)m * Nout + n) = o;
            } else {
                f16x4 hv;
                hv[0] = (half_t)v[0]; hv[1] = (half_t)v[1];
                hv[2] = (half_t)v[2]; hv[3] = (half_t)v[3];
                const int p = (n * 2) ^ ((m & 7) << 4);
                *(f16x4*)((char*)Out + (size_t)m * ROWB + p) = hv;
            }
        }
        if (EMIT) {  // reduce over the 4 l4-lanes sharing this row, one atomic
            rsum += __shfl_xor(rsum, 16, 64);
            rsum += __shfl_xor(rsum, 32, 64);
            if (l4 == 0) atomicAdd(msum_out + m, rsum);
        }
    }
}

extern "C" void kernel_launch(void* const* d_in, const int* in_sizes, int n_in,
                              void* d_out, int out_size, void* d_ws, size_t ws_size,
                              hipStream_t stream) {
    const float* x  = (const float*)d_in[0];  // [2048,1024]
    const float* We = (const float*)d_in[1];  // [1024,1024]
    const float* be = (const float*)d_in[2];  // [1024]
    const float* W  = (const float*)d_in[3];  // [3,1024,1024]
    const float* b  = (const float*)d_in[4];  // [3,1024]
    const float* Wh = (const float*)d_in[5];  // [512,1024]
    const float* bh = (const float*)d_in[6];  // [512]

    const int B = 2048, H = 1024, O = 512;

    half_t* s0   = (half_t*)d_ws;                   // x16 / H0 / H2
    half_t* s1   = s0 + (size_t)B * H;              // E / H1
    half_t* We16 = s1 + (size_t)B * H;
    half_t* W16  = We16 + (size_t)H * H;
    half_t* Wh16 = W16 + (size_t)3 * H * H;
    float*  msum = (float*)(Wh16 + (size_t)O * H);  // 3 x 2048 f32
    float*  out  = (float*)d_out;

    convert_all<<<6656, 256, 0, stream>>>(x, We, W, Wh, s0, We16, W16, Wh16, msum);

    // E = x @ We^T + be; emit |E| row sums -> msum0
    gemm8w<0, true ><<<256, 512, 0, stream>>>(s0, We16, be, nullptr, msum, s1, H);
    // H0 = m0 * 0.5*tanh(E @ W0^T + b0); emit -> msum1
    gemm8w<1, true ><<<256, 512, 0, stream>>>(s1, W16, b, msum, msum + 2048, s0, H);
    // H1; emit -> msum2
    gemm8w<1, true ><<<256, 512, 0, stream>>>(s0, W16 + (size_t)H * H, b + H,
                                              msum + 2048, msum + 4096, s1, H);
    // H2 (no emit)
    gemm8w<1, false><<<256, 512, 0, stream>>>(s1, W16 + (size_t)2 * H * H, b + 2 * H,
                                              msum + 4096, nullptr, s0, H);
    // head
    gemm8w<2, false><<<128, 512, 0, stream>>>(s0, Wh16, bh, nullptr, nullptr, out, O);
}